// Round 7
// baseline (843.607 us; speedup 1.0000x reference)
//
#include <hip/hip_runtime.h>

typedef float f32x4 __attribute__((ext_vector_type(4)));
typedef float f32x2 __attribute__((ext_vector_type(2)));
typedef short bf16x8 __attribute__((ext_vector_type(8)));
typedef unsigned short ushort_t;
typedef unsigned int uint_t;

#define LOG2E  1.442695041f
#define LOG2E2 2.885390082f

// ---------------- Threefry-2x32 (20 rounds), exact JAX semantics (verified r1) ----------------
__device__ __forceinline__ unsigned rotl32(unsigned x, unsigned r){ return (x << r) | (x >> (32u - r)); }

__device__ __forceinline__ void tf2x32(unsigned k0, unsigned k1, unsigned c0, unsigned c1,
                                       unsigned &o0, unsigned &o1){
  unsigned ks2 = k0 ^ k1 ^ 0x1BD11BDAu;
  unsigned x0 = c0 + k0, x1 = c1 + k1;
#define TFR(r) { x0 += x1; x1 = rotl32(x1, r); x1 ^= x0; }
  TFR(13) TFR(15) TFR(26) TFR(6)
  x0 += k1;  x1 += ks2 + 1u;
  TFR(17) TFR(29) TFR(16) TFR(24)
  x0 += ks2; x1 += k0 + 2u;
  TFR(13) TFR(15) TFR(26) TFR(6)
  x0 += k0;  x1 += k1 + 3u;
  TFR(17) TFR(29) TFR(16) TFR(24)
  x0 += k1;  x1 += ks2 + 4u;
  TFR(13) TFR(15) TFR(26) TFR(6)
  x0 += ks2; x1 += k0 + 5u;
#undef TFR
  o0 = x0; o1 = x1;
}

__device__ __forceinline__ float bits_to_u01(unsigned bits){
  return __uint_as_float((bits >> 9) | 0x3f800000u) - 1.0f;
}

// XLA ErfInv32 (Giles polynomial) — verified r1
__device__ __forceinline__ float erfinv_f(float x){
  float w = -log1pf(-x * x);
  float p;
  if (w < 5.0f){
    w -= 2.5f;
    p = 2.81022636e-08f;
    p = 3.43273939e-07f + p * w;
    p = -3.5233877e-06f + p * w;
    p = -4.39150654e-06f + p * w;
    p = 0.00021858087f + p * w;
    p = -0.00125372503f + p * w;
    p = -0.00417768164f + p * w;
    p = 0.246640727f + p * w;
    p = 1.50140941f + p * w;
  } else {
    w = sqrtf(w) - 3.0f;
    p = -0.000200214257f;
    p = 0.000100950558f + p * w;
    p = 0.00134934322f + p * w;
    p = -0.00367342844f + p * w;
    p = 0.00573950773f + p * w;
    p = -0.0076224613f + p * w;
    p = 0.00943887047f + p * w;
    p = 1.00167406f + p * w;
    p = 2.83297682f + p * w;
  }
  return p * x;
}

__device__ __forceinline__ ushort_t f2bf(float f){
  unsigned u = __float_as_uint(f);
  unsigned r = u + 0x7fffu + ((u >> 16) & 1u);
  return (ushort_t)(r >> 16);
}

__device__ __forceinline__ float norm_draw(unsigned sk0, unsigned sk1, unsigned g, unsigned e){
  unsigned gk0, gk1, b0, b1;
  tf2x32(sk0, sk1, 0u, g, gk0, gk1);
  tf2x32(gk0, gk1, 0u, e, b0, b1);
  unsigned bits = b0 ^ b1;
  float u01 = bits_to_u01(bits);
  const float LO = __uint_as_float(0xBF7FFFFFu);
  float u = u01 * 2.0f + LO;
  u = fmaxf(LO, u);
  return 1.41421356237f * erfinv_f(u);
}

__device__ __forceinline__ float softplus_f(float r){ return log1pf(expf(r)); }
__device__ __forceinline__ float gscale(int gate){ return gate == 2 ? LOG2E2 : LOG2E; }

// ---------------- fast device math for main kernel ----------------
__device__ __forceinline__ float fexp2(float x){
  float r;
  asm("v_exp_f32 %0, %1" : "=v"(r) : "v"(x));
  return r;
}
__device__ __forceinline__ float frcp(float x){ return __builtin_amdgcn_rcpf(x); }

// gates are PRE-SCALED: i,f,o by log2e; g by 2*log2e (folded into weights in prep)
__device__ __forceinline__ float lstm_act(float gi, float gf, float gg, float go, float& c){
  float Ef = fexp2(gf);
  float sf = Ef * frcp(1.0f + Ef);
  float EiN = fexp2(-gi);
  float Eg  = fexp2(gg);
  float cn = sf * c + (Eg - 1.0f) * frcp((1.0f + EiN) * (Eg + 1.0f));
  c = cn;
  float EoN = fexp2(-go);
  float Ec  = fexp2(cn * LOG2E2);
  return (Ec - 1.0f) * frcp((1.0f + EoN) * (Ec + 1.0f));
}

__device__ __forceinline__ float cp_lo(unsigned w){ return __uint_as_float(w << 16); }
__device__ __forceinline__ float cp_hi(unsigned w){ return __uint_as_float(w & 0xFFFF0000u); }
__device__ __forceinline__ unsigned cp_pack(float lo, float hi){
  return (__float_as_uint(hi) & 0xFFFF0000u) | (__float_as_uint(lo) >> 16);
}

// ---------------- geometry ----------------
constexpr int P0 = 136;   // H0 pitch (elems): h0[128] + pad
constexpr int P1 = 264;   // H1 pitch: h1[128] | hd/x[128] | pad

// ---------------- fused prep ----------------
__global__ void prep_all(
    const float* __restrict__ wih0,  const float* __restrict__ whh0,
    const float* __restrict__ bih0,  const float* __restrict__ bhh0,
    const float* __restrict__ wih1,  const float* __restrict__ whh1,
    const float* __restrict__ bih1,  const float* __restrict__ bhh1,
    const float* __restrict__ din_wmu, const float* __restrict__ din_wrho,
    const float* __restrict__ din_bmu, const float* __restrict__ din_brho,
    const float* __restrict__ dhid_wmu, const float* __restrict__ dhid_wrho,
    const float* __restrict__ dhid_bmu, const float* __restrict__ dhid_brho,
    const float* __restrict__ out_wmu, const float* __restrict__ out_wrho,
    const float* __restrict__ out_bmu, const float* __restrict__ out_brho,
    ushort_t* __restrict__ whh0b, ushort_t* __restrict__ w1e,
    float* __restrict__ wx0s, float* __restrict__ b0s, float* __restrict__ b1s,
    ushort_t* __restrict__ dwhidb, float* __restrict__ dwinb, float* __restrict__ dbsum,
    ushort_t* __restrict__ dwoutb, float* __restrict__ dbout,
    unsigned* __restrict__ maskM, float* __restrict__ out){
  const int blk = blockIdx.x, tid = threadIdx.x;

  if (blk < 4096){
    // dropout mask, BLOCK-MAJOR: word = mb*4096 + t*512 + hj*4 + bw, bit i -> batch mb*128+bw*32+i
    unsigned w = blk * 256u + tid;
    unsigned mb = w >> 12, t = (w >> 9) & 7u, hj = (w >> 2) & 127u, bw = w & 3u;
    unsigned word = 0;
    #pragma unroll 4
    for (int i = 0; i < 32; ++i){
      unsigned ctr = (mb * 128u + bw * 32u + i) * 1024u + t * 128u + hj;  // JAX flat idx b*1024+t*128+h
      unsigned o0, o1;
      tf2x32(0u, 1u, 0u, ctr, o0, o1);
      float u = bits_to_u01(o0 ^ o1);
      word |= (u < 0.9f ? 1u : 0u) << i;
    }
    maskM[w] = word;
  } else if (blk < 4872){
    int idx = (blk - 4096) * 256 + tid;   // < 198656 exact
    if (idx < 65536){
      int row = idx >> 7;
      whh0b[idx] = f2bf(whh0[idx] * gscale(row >> 7));
    } else if (idx < 196608){
      int j = idx - 65536;
      int row = j >> 8, col = j & 255;
      float v = col < 128 ? whh1[row * 128 + col] : wih1[row * 128 + (col - 128)];
      w1e[j] = f2bf(v * gscale(row >> 7));
    } else if (idx < 197632){
      int j = idx - 196608;   // < 1024, row = j>>1
      wx0s[j] = wih0[j] * gscale(j >> 8);
    } else if (idx < 198144){
      int j = idx - 197632;
      b0s[j] = (bih0[j] + bhh0[j]) * gscale(j >> 7);
    } else {
      int j = idx - 198144;
      b1s[j] = (bih1[j] + bhh1[j]) * gscale(j >> 7);
    }
  } else if (blk < 8113){
    int idx = (blk - 4872) * 256 + tid;
    if (idx < 829488){
      int s = idx / 69124, r = idx - s * 69124;
      unsigned sk0, sk1;
      tf2x32(0u, 2u, 0u, (unsigned)s, sk0, sk1);   // split(key(2), 12)
      if (r < 65536){
        int row = r >> 7;
        float v = dhid_wmu[r] + softplus_f(dhid_wrho[r]) * norm_draw(sk0, sk1, 2u, (unsigned)r);
        dwhidb[s * 65536 + r] = f2bf(v * gscale(row >> 7));
      } else if (r < 66560){
        int j = r - 65536;   // row = j>>1
        float v = din_wmu[j] + softplus_f(din_wrho[j]) * norm_draw(sk0, sk1, 0u, (unsigned)j);
        dwinb[s * 1024 + j] = v * gscale(j >> 8);
      } else if (r < 67072){
        int j = r - 66560;
        float v1 = din_bmu[j]  + softplus_f(din_brho[j])  * norm_draw(sk0, sk1, 1u, (unsigned)j);
        float v2 = dhid_bmu[j] + softplus_f(dhid_brho[j]) * norm_draw(sk0, sk1, 3u, (unsigned)j);
        dbsum[s * 512 + j] = (v1 + v2) * gscale(j >> 7);
      } else if (r < 69120){
        int j = r - 67072;
        ushort_t v = 0;
        if (j < 512)
          v = f2bf(out_wmu[j] + softplus_f(out_wrho[j]) * norm_draw(sk0, sk1, 4u, (unsigned)j));
        dwoutb[s * 2048 + j] = v;
      } else {
        int j = r - 69120;
        dbout[s * 4 + j] = out_bmu[j] + softplus_f(out_brho[j]) * norm_draw(sk0, sk1, 5u, (unsigned)j);
      }
    }
  } else {
    // KL: 267 blocks, atomicAdd into out[1572864] (zeroed by hipMemsetAsync)
    int idx = (blk - 8113) * 256 + tid;
    float s = 0.f;
    if (idx < 68100){
      float mu, rho;
      if (idx < 1024){ mu = din_wmu[idx]; rho = din_wrho[idx]; }
      else if (idx < 1536){ mu = din_bmu[idx-1024]; rho = din_brho[idx-1024]; }
      else if (idx < 67072){ mu = dhid_wmu[idx-1536]; rho = dhid_wrho[idx-1536]; }
      else if (idx < 67584){ mu = dhid_bmu[idx-67072]; rho = dhid_brho[idx-67072]; }
      else if (idx < 68096){ mu = out_wmu[idx-67584]; rho = out_wrho[idx-67584]; }
      else { mu = out_bmu[idx-68096]; rho = out_brho[idx-68096]; }
      float stdv = softplus_f(rho);
      s = logf(0.1f / stdv) + (stdv * stdv + mu * mu) * 50.0f - 0.5f;
    }
    __shared__ float red[256];
    red[tid] = s;
    __syncthreads();
    for (int off = 128; off > 0; off >>= 1){
      if (tid < off) red[tid] += red[tid + off];
      __syncthreads();
    }
    if (tid == 0) atomicAdd(out + 1572864, red[0]);
  }
}

// ---------------- GEMM helpers: streaming B, 16+16-reg ping-pong ----------------
__device__ __forceinline__ void preB(const ushort_t* __restrict__ W, int WROW,
                                     int hj, int lg, bf16x8 (&B)[4]){
  const ushort_t* wp = W + (size_t)hj * WROW + 8 * lg;
  #pragma unroll
  for (int g = 0; g < 4; ++g)
    B[g] = *(const bf16x8*)(wp + (size_t)(128 * g) * WROW);
}

#define ZACC(acc) { _Pragma("unroll") for (int g_=0;g_<4;++g_) _Pragma("unroll") for (int m_=0;m_<4;++m_) acc[g_][m_] = (f32x4){0.f,0.f,0.f,0.f}; }

// K=128 gemm over batch-half H; Bc holds chunk ki=0 (preloaded before the paired pointwise)
template<int H, int P>
__device__ __forceinline__ void gemm_w128(const ushort_t* __restrict__ Hl,
                                          const ushort_t* __restrict__ W,
                                          int lx, int lg, int hj,
                                          f32x4 (&acc)[4][4], bf16x8 (&Bc)[4]){
  ZACC(acc);
  const ushort_t* wp = W + (size_t)hj * 128 + 8 * lg;
  #pragma unroll
  for (int ki = 0; ki < 4; ++ki){
    bf16x8 Bn[4];
    if (ki < 3){
      #pragma unroll
      for (int g = 0; g < 4; ++g)
        Bn[g] = *(const bf16x8*)(wp + (size_t)(128 * g) * 128 + 32 * (ki + 1));
    }
    #pragma unroll
    for (int m = 0; m < 4; ++m){
      bf16x8 a = *(const bf16x8*)(Hl + (64 * H + 16 * m + lx) * P + 32 * ki + 8 * lg);
      #pragma unroll
      for (int g = 0; g < 4; ++g)
        acc[g][m] = __builtin_amdgcn_mfma_f32_16x16x32_bf16(a, Bc[g], acc[g][m], 0, 0, 0);
    }
    if (ki < 3){
      #pragma unroll
      for (int g = 0; g < 4; ++g) Bc[g] = Bn[g];
    }
  }
}

// K=256 gemm (w1e: [512][256]) over batch-half H of H1s ([h1|hd] cols 0..255)
template<int H>
__device__ __forceinline__ void gemm_w256(const ushort_t* __restrict__ H1,
                                          const ushort_t* __restrict__ W,
                                          int lx, int lg, int hj,
                                          f32x4 (&acc)[4][4], bf16x8 (&Bc)[4]){
  ZACC(acc);
  const ushort_t* wp = W + (size_t)hj * 256 + 8 * lg;
  #pragma unroll
  for (int ki = 0; ki < 8; ++ki){
    bf16x8 Bn[4];
    if (ki < 7){
      #pragma unroll
      for (int g = 0; g < 4; ++g)
        Bn[g] = *(const bf16x8*)(wp + (size_t)(128 * g) * 256 + 32 * (ki + 1));
    }
    #pragma unroll
    for (int m = 0; m < 4; ++m){
      bf16x8 a = *(const bf16x8*)(H1 + (64 * H + 16 * m + lx) * P1 + 32 * ki + 8 * lg);
      #pragma unroll
      for (int g = 0; g < 4; ++g)
        acc[g][m] = __builtin_amdgcn_mfma_f32_16x16x32_bf16(a, Bc[g], acc[g][m], 0, 0, 0);
    }
    if (ki < 7){
      #pragma unroll
      for (int g = 0; g < 4; ++g) Bc[g] = Bn[g];
    }
  }
}

// ---------------- pointwise halves (identical to r4/r6, which passed) ----------------
template<int H>
__device__ __forceinline__ void pw0_half(int t, f32x4 (&acc)[4][4], unsigned* c0p,
    const float (&bv)[4], const float (&wav)[4], const float (&wbv)[4], uint4 mk,
    ushort_t* __restrict__ H0, ushort_t* __restrict__ H1, const float* __restrict__ OBSs,
    int hj, int lg){
  #pragma unroll
  for (int m = 0; m < 4; ++m){
    unsigned cwA = c0p[H*8 + m*2], cwB = c0p[H*8 + m*2 + 1];
    float cf0 = cp_lo(cwA), cf1 = cp_hi(cwA), cf2 = cp_lo(cwB), cf3 = cp_hi(cwB);
    const int wsel = H*2 + (m >> 1);
    unsigned mkw = wsel == 0 ? mk.x : wsel == 1 ? mk.y : wsel == 2 ? mk.z : mk.w;
    #pragma unroll
    for (int e = 0; e < 4; ++e){
      float& cf = e == 0 ? cf0 : e == 1 ? cf1 : e == 2 ? cf2 : cf3;
      int row = 64*H + 16*m + 4*lg + e;
      f32x2 xv = *(const f32x2*)(OBSs + row * 16 + 2 * t);
      float gi = acc[0][m][e] + bv[0] + xv.x * wav[0] + xv.y * wbv[0];
      float gf = acc[1][m][e] + bv[1] + xv.x * wav[1] + xv.y * wbv[1];
      float gg = acc[2][m][e] + bv[2] + xv.x * wav[2] + xv.y * wbv[2];
      float go = acc[3][m][e] + bv[3] + xv.x * wav[3] + xv.y * wbv[3];
      float hv = lstm_act(gi, gf, gg, go, cf);
      H0[row * P0 + hj] = f2bf(hv);
      unsigned keep = (mkw >> (((m & 1) << 4) + 4 * lg + e)) & 1u;
      H1[row * P1 + 128 + hj] = keep ? f2bf(hv * (1.0f / 0.9f)) : (ushort_t)0;
    }
    c0p[H*8 + m*2]     = cp_pack(cf0, cf1);
    c0p[H*8 + m*2 + 1] = cp_pack(cf2, cf3);
  }
}

template<int H>
__device__ __forceinline__ void pw1_half(f32x4 (&acc)[4][4], unsigned* c1p,
    const float (&bv)[4], ushort_t* __restrict__ H1, int hj, int lg){
  #pragma unroll
  for (int m = 0; m < 4; ++m){
    unsigned cwA = c1p[H*8 + m*2], cwB = c1p[H*8 + m*2 + 1];
    float cf0 = cp_lo(cwA), cf1 = cp_hi(cwA), cf2 = cp_lo(cwB), cf3 = cp_hi(cwB);
    #pragma unroll
    for (int e = 0; e < 4; ++e){
      float& cf = e == 0 ? cf0 : e == 1 ? cf1 : e == 2 ? cf2 : cf3;
      int row = 64*H + 16*m + 4*lg + e;
      float gi = acc[0][m][e] + bv[0];
      float gf = acc[1][m][e] + bv[1];
      float gg = acc[2][m][e] + bv[2];
      float go = acc[3][m][e] + bv[3];
      float hv = lstm_act(gi, gf, gg, go, cf);
      H1[row * P1 + hj] = f2bf(hv);
    }
    c1p[H*8 + m*2]     = cp_pack(cf0, cf1);
    c1p[H*8 + m*2 + 1] = cp_pack(cf2, cf3);
  }
}

template<int H>
__device__ __forceinline__ void pwd_half(f32x4 (&acc)[4][4], unsigned* c1p,
    const float (&bv)[4], const float (&wav)[4], const float (&wbv)[4],
    ushort_t* __restrict__ H1, const float* __restrict__ XDs, int hj, int lg){
  #pragma unroll
  for (int m = 0; m < 4; ++m){
    unsigned cwA = c1p[H*8 + m*2], cwB = c1p[H*8 + m*2 + 1];
    float cf0 = cp_lo(cwA), cf1 = cp_hi(cwA), cf2 = cp_lo(cwB), cf3 = cp_hi(cwB);
    #pragma unroll
    for (int e = 0; e < 4; ++e){
      float& cf = e == 0 ? cf0 : e == 1 ? cf1 : e == 2 ? cf2 : cf3;
      int row = 64*H + 16*m + 4*lg + e;
      f32x2 xv = *(const f32x2*)(XDs + 2 * row);
      float gi = acc[0][m][e] + bv[0] + xv.x * wav[0] + xv.y * wbv[0];
      float gf = acc[1][m][e] + bv[1] + xv.x * wav[1] + xv.y * wbv[1];
      float gg = acc[2][m][e] + bv[2] + xv.x * wav[2] + xv.y * wbv[2];
      float go = acc[3][m][e] + bv[3] + xv.x * wav[3] + xv.y * wbv[3];
      float hv = lstm_act(gi, gf, gg, go, cf);
      H1[row * P1 + hj] = f2bf(hv);
    }
    c1p[H*8 + m*2]     = cp_pack(cf0, cf1);
    c1p[H*8 + m*2 + 1] = cp_pack(cf2, cf3);
  }
}

// ---------------- decoder out-head: per-wave 16-row MFMA tile (builtin) ----------------
__device__ __forceinline__ void out_head(int s, int mt, int lx, int lg, int b0,
    const ushort_t* __restrict__ H1, const ushort_t* __restrict__ dwoutb,
    const float* __restrict__ dbout, float* __restrict__ XDs, float* __restrict__ out){
  const ushort_t* wp = dwoutb + (size_t)s * 2048 + lx * 128 + 8 * lg;
  const ushort_t* hp = H1 + (16 * mt + lx) * P1 + 8 * lg;
  f32x4 accO = {0.f, 0.f, 0.f, 0.f};
  accO = __builtin_amdgcn_mfma_f32_16x16x32_bf16(*(const bf16x8*)(hp),      *(const bf16x8*)(wp),      accO, 0, 0, 0);
  accO = __builtin_amdgcn_mfma_f32_16x16x32_bf16(*(const bf16x8*)(hp + 32), *(const bf16x8*)(wp + 32), accO, 0, 0, 0);
  accO = __builtin_amdgcn_mfma_f32_16x16x32_bf16(*(const bf16x8*)(hp + 64), *(const bf16x8*)(wp + 64), accO, 0, 0, 0);
  accO = __builtin_amdgcn_mfma_f32_16x16x32_bf16(*(const bf16x8*)(hp + 96), *(const bf16x8*)(wp + 96), accO, 0, 0, 0);
  if (lx < 4){
    float bo = dbout[s * 4 + lx];
    #pragma unroll
    for (int e = 0; e < 4; ++e){
      int row = 16 * mt + 4 * lg + e;
      float v = accO[e] + bo;
      int gb = b0 + row;
      if (lx < 2){
        out[gb * 24 + s * 2 + lx] = v;
        XDs[2 * row + lx] = v;             // mu feedback
      } else {
        out[786432 + gb * 24 + s * 2 + (lx - 2)] = fminf(fmaxf(v, -4.0f), 2.0f);
      }
    }
  }
}

// ---------------- main fused kernel: 512 thr (8 waves), BT=128, grid 256 (1 block/CU) ----------------
// LDS 109KB -> 1 block/CU -> 2 waves/SIMD physically. amdgpu_waves_per_eu(2,2) pins the
// register allocator to that occupancy: 256-VGPR budget, working set ~180 -> no spill.
__global__ __launch_bounds__(512)
__attribute__((amdgpu_waves_per_eu(2, 2)))
void lstm_main(
    const float* __restrict__ obs,
    const ushort_t* __restrict__ whh0b,   // [512][128] scaled
    const ushort_t* __restrict__ w1e,     // [512][256] scaled (whh1|wih1)
    const float* __restrict__ wx0s,       // [512][2] scaled
    const float* __restrict__ b0s,        // [512] scaled
    const float* __restrict__ b1s,        // [512] scaled
    const ushort_t* __restrict__ dwhidb,  // [12][512][128] scaled
    const float* __restrict__ dwinb,      // [12][512][2] scaled
    const float* __restrict__ dbsum,      // [12][512] scaled
    const ushort_t* __restrict__ dwoutb,  // [12][16][128] (unscaled, rows 4-15 = 0)
    const float* __restrict__ dbout,      // [12][4]
    const unsigned* __restrict__ maskM,   // [256][8][128][4] block-major
    float* __restrict__ out){
  __shared__ __align__(16) ushort_t H0s[128 * P0];   // 34816 B
  __shared__ __align__(16) ushort_t H1s[128 * P1];   // 67584 B
  __shared__ __align__(16) float OBSs[128 * 16];     // 8192 B
  __shared__ float XDs[256];                         // 1024 B

  const int tid = threadIdx.x;
  const int wv = tid >> 6, l = tid & 63, lx = l & 15, lg = l >> 4;
  const int hj = 16 * wv + lx;
  const int b0 = blockIdx.x * 128;

  // stage obs (2048 f32 = 512 f32x4)
  ((f32x4*)OBSs)[tid] = ((const f32x4*)(obs + (size_t)b0 * 16))[tid];
  {
    uint_t* p = (uint_t*)H0s;
    #pragma unroll 1
    for (int i = tid; i < 128 * P0 / 2; i += 512) p[i] = 0;
    uint_t* q = (uint_t*)H1s;
    #pragma unroll 1
    for (int i = tid; i < 128 * P1 / 2; i += 512) q[i] = 0;
  }

  float b0sv[4], wa0v[4], wb0v[4], b1sv[4];
  #pragma unroll
  for (int g = 0; g < 4; ++g){
    int j = 128 * g + hj;
    b0sv[g] = b0s[j];
    f32x2 w = *(const f32x2*)(wx0s + 2 * j);
    wa0v[g] = w.x; wb0v[g] = w.y;
    b1sv[g] = b1s[j];
  }
  unsigned c0p[16], c1p[16];
  #pragma unroll
  for (int i = 0; i < 16; ++i){ c0p[i] = 0; c1p[i] = 0; }

  f32x4 acc[4][4];
  bf16x8 Bc[4];

  __syncthreads();

  // ================= encoder: 8 steps, 4 phases each =================
  #pragma unroll 1
  for (int t = 0; t < 8; ++t){
    // P1: [pw1-h1(t-1) || g0-h0(t)]
    preB(whh0b, 128, hj, lg, Bc);
    const uint4 mk = *(const uint4*)(maskM + (size_t)blockIdx.x * 4096 + (size_t)t * 512 + (size_t)hj * 4);
    if (t > 0) pw1_half<1>(acc, c1p, b1sv, H1s, hj, lg);
    gemm_w128<0, P0>(H0s, whh0b, lx, lg, hj, acc, Bc);
    __syncthreads();
    // P2: [pw0-h0 || g0-h1]
    preB(whh0b, 128, hj, lg, Bc);
    pw0_half<0>(t, acc, c0p, b0sv, wa0v, wb0v, mk, H0s, H1s, OBSs, hj, lg);
    gemm_w128<1, P0>(H0s, whh0b, lx, lg, hj, acc, Bc);
    __syncthreads();
    // P3: [pw0-h1 || g1-h0]
    preB(w1e, 256, hj, lg, Bc);
    pw0_half<1>(t, acc, c0p, b0sv, wa0v, wb0v, mk, H0s, H1s, OBSs, hj, lg);
    gemm_w256<0>(H1s, w1e, lx, lg, hj, acc, Bc);
    __syncthreads();
    // P4: [pw1-h0 || g1-h1]
    preB(w1e, 256, hj, lg, Bc);
    pw1_half<0>(acc, c1p, b1sv, H1s, hj, lg);
    gemm_w256<1>(H1s, w1e, lx, lg, hj, acc, Bc);
    __syncthreads();
  }

  // ================= transition = D1(0): [pw1-h1(7) || gdec-h0(0)] + XDs init =================
  preB(dwhidb, 128, hj, lg, Bc);
  pw1_half<1>(acc, c1p, b1sv, H1s, hj, lg);
  gemm_w128<0, P1>(H1s, dwhidb, lx, lg, hj, acc, Bc);
  if (tid < 256) XDs[tid] = OBSs[(tid >> 1) * 16 + 14 + (tid & 1)];
  __syncthreads();

  // ================= decoder: 12 steps, 2 phases each =================
  #pragma unroll 1
  for (int s = 0; s < 12; ++s){
    const ushort_t* dw_cur = dwhidb + (size_t)s * 65536;
    float bdv[4], wdx[4], wdy[4];
    #pragma unroll
    for (int g = 0; g < 4; ++g){
      int j = 128 * g + hj;
      bdv[g] = dbsum[s * 512 + j];
      f32x2 w = *(const f32x2*)(dwinb + 2 * (s * 512 + j));
      wdx[g] = w.x; wdy[g] = w.y;
    }
    // D2(s): [pwd-h0(s) || g-h1(s) || oh-h1(s-1)]
    preB(dw_cur, 128, hj, lg, Bc);
    pwd_half<0>(acc, c1p, bdv, wdx, wdy, H1s, XDs, hj, lg);
    gemm_w128<1, P1>(H1s, dw_cur, lx, lg, hj, acc, Bc);
    if (s > 0 && wv >= 4) out_head(s - 1, wv, lx, lg, b0, H1s, dwoutb, dbout, XDs, out);
    __syncthreads();
    // D1(s+1): [pwd-h1(s) || g-h0(s+1) || oh-h0(s)]
    if (s < 11){
      const ushort_t* dw_next = dwhidb + (size_t)(s + 1) * 65536;
      preB(dw_next, 128, hj, lg, Bc);
      pwd_half<1>(acc, c1p, bdv, wdx, wdy, H1s, XDs, hj, lg);
      gemm_w128<0, P1>(H1s, dw_next, lx, lg, hj, acc, Bc);
      if (wv < 4) out_head(s, wv, lx, lg, b0, H1s, dwoutb, dbout, XDs, out);
      __syncthreads();
    } else {
      pwd_half<1>(acc, c1p, bdv, wdx, wdy, H1s, XDs, hj, lg);
      if (wv < 4) out_head(11, wv, lx, lg, b0, H1s, dwoutb, dbout, XDs, out);
      __syncthreads();
      if (wv >= 4) out_head(11, wv, lx, lg, b0, H1s, dwoutb, dbout, XDs, out);
    }
  }
}

// ---------------- launch ----------------
extern "C" void kernel_launch(void* const* d_in, const int* in_sizes, int n_in,
                              void* d_out, int out_size, void* d_ws, size_t ws_size,
                              hipStream_t stream){
  (void)in_sizes; (void)n_in; (void)out_size; (void)ws_size;
  const float* obs   = (const float*)d_in[0];
  const float* wih0  = (const float*)d_in[1];
  const float* whh0  = (const float*)d_in[2];
  const float* bih0  = (const float*)d_in[3];
  const float* bhh0  = (const float*)d_in[4];
  const float* wih1  = (const float*)d_in[5];
  const float* whh1  = (const float*)d_in[6];
  const float* bih1  = (const float*)d_in[7];
  const float* bhh1  = (const float*)d_in[8];
  const float* din_wmu  = (const float*)d_in[9];
  const float* din_wrho = (const float*)d_in[10];
  const float* din_bmu  = (const float*)d_in[11];
  const float* din_brho = (const float*)d_in[12];
  const float* dhid_wmu  = (const float*)d_in[13];
  const float* dhid_wrho = (const float*)d_in[14];
  const float* dhid_bmu  = (const float*)d_in[15];
  const float* dhid_brho = (const float*)d_in[16];
  const float* out_wmu  = (const float*)d_in[17];
  const float* out_wrho = (const float*)d_in[18];
  const float* out_bmu  = (const float*)d_in[19];
  const float* out_brho = (const float*)d_in[20];

  char* wsb = (char*)d_ws;
  ushort_t* whh0b  = (ushort_t*)(wsb + 0);         // 131072
  ushort_t* w1e    = (ushort_t*)(wsb + 131072);    // 262144
  float*    wx0s   = (float*)(wsb + 393216);       // 4096
  float*    b0s    = (float*)(wsb + 397312);       // 2048
  float*    b1s    = (float*)(wsb + 399360);       // 2048
  ushort_t* dwhidb = (ushort_t*)(wsb + 401408);    // 1572864
  float*    dwinb  = (float*)(wsb + 1974272);      // 49152
  float*    dbsum  = (float*)(wsb + 2023424);      // 24576
  ushort_t* dwoutb = (ushort_t*)(wsb + 2048000);   // 49152
  float*    dbout  = (float*)(wsb + 2097152);      // 192
  unsigned* maskM  = (unsigned*)(wsb + 2097344);   // 4194304

  // zero the KL accumulator slot (prep atomically adds into it)
  hipMemsetAsync((float*)d_out + 1572864, 0, 4, stream);

  prep_all<<<8380, 256, 0, stream>>>(
      wih0, whh0, bih0, bhh0, wih1, whh1, bih1, bhh1,
      din_wmu, din_wrho, din_bmu, din_brho,
      dhid_wmu, dhid_wrho, dhid_bmu, dhid_brho,
      out_wmu, out_wrho, out_bmu, out_brho,
      whh0b, w1e, wx0s, b0s, b1s, dwhidb, dwinb, dbsum, dwoutb, dbout,
      maskM, (float*)d_out);

  lstm_main<<<256, 512, 0, stream>>>(obs, whh0b, w1e, wx0s, b0s, b1s,
                                     dwhidb, dwinb, dbsum, dwoutb, dbout,
                                     maskM, (float*)d_out);
}